// Round 4
// baseline (2407.292 us; speedup 1.0000x reference)
//
#include <hip/hip_runtime.h>
#include <hip/hip_bf16.h>
#include <math.h>

// SAM vision layer: LN1 -> windowed attention (decomposed rel-pos bias) -> proj
// + residual -> LN2 -> MLP(GELU exact) -> residual.
// B=8, H=W=64, HS=768, NH=12, HD=64, WS=14 -> 200 windows x 196 tokens.

#define HS 768
#define NHEADS 12
#define HD 64
#define WSZ 14
#define TOK 196
#define HWDIM 64
#define NSIDE 5
#define WIN_PER_B 25
#define WCHUNK 25
#define MCH 4900        // rows per window chunk = 25*196
#define MLPCH 4096      // tokens per MLP chunk (32768/8)

typedef __attribute__((ext_vector_type(8))) short short8;
typedef __attribute__((ext_vector_type(4))) float floatx4;

__device__ __forceinline__ float bf2f(unsigned short u) {
    union { unsigned int i; float f; } w; w.i = ((unsigned int)u) << 16; return w.f;
}
__device__ __forceinline__ unsigned short f2bu(float f) {
    __hip_bfloat16 h = __float2bfloat16(f);
    return *(unsigned short*)&h;
}

// async global->LDS, 16B per lane; lds dest = wave-uniform base + lane*16
__device__ __forceinline__ void gload16(const unsigned short* g, unsigned short* l) {
    __builtin_amdgcn_global_load_lds(
        (const __attribute__((address_space(1))) unsigned int*)g,
        (__attribute__((address_space(3))) unsigned int*)l, 16, 0, 0);
}

// ---- fp32 -> bf16 transposed convert: src[K][N] -> dst[N][K] ----
__global__ __launch_bounds__(256)
void cvt_t_k(const float* __restrict__ src, __hip_bfloat16* __restrict__ dst,
             int K, int N) {
    int idx = blockIdx.x * 256 + threadIdx.x;
    if (idx >= K * N) return;
    int k = idx / N, n = idx - k * N;
    dst[(size_t)n * K + k] = __float2bfloat16(src[idx]);
}

// ---- LayerNorm over HS=768, one block per row; GATHER=1 scatter-writes the
// row to its window-token slot (pad rows stay zero from the memset). ----
template<int GATHER>
__global__ __launch_bounds__(256)
void ln_k(const float* __restrict__ x, const float* __restrict__ g,
          const float* __restrict__ b, __hip_bfloat16* __restrict__ y) {
    int row = blockIdx.x;
    const float* xr = x + (size_t)row * HS;
    int tid = threadIdx.x;
    float v0 = xr[tid], v1 = xr[tid + 256], v2 = xr[tid + 512];
    float s = v0 + v1 + v2;
    float q = v0 * v0 + v1 * v1 + v2 * v2;
    for (int off = 32; off > 0; off >>= 1) {
        s += __shfl_down(s, off, 64);
        q += __shfl_down(q, off, 64);
    }
    __shared__ float ss[4], sq[4];
    int wave = tid >> 6, lane = tid & 63;
    if (lane == 0) { ss[wave] = s; sq[wave] = q; }
    __syncthreads();
    if (tid == 0) {
        float S = ss[0] + ss[1] + ss[2] + ss[3];
        float Q = sq[0] + sq[1] + sq[2] + sq[3];
        float mu = S * (1.0f / HS);
        float var = Q * (1.0f / HS) - mu * mu;
        ss[0] = mu;
        sq[0] = rsqrtf(var + 1e-6f);
    }
    __syncthreads();
    float mu = ss[0], rstd = sq[0];
    int drow = row;
    if (GATHER) {
        int bb = row >> 12, rem = row & 4095;
        int h = rem >> 6, w = rem & 63;
        int win = bb * WIN_PER_B + (h / WSZ) * NSIDE + (w / WSZ);
        int tok = (h % WSZ) * WSZ + (w % WSZ);
        drow = win * TOK + tok;
    }
    __hip_bfloat16* yr = y + (size_t)drow * HS;
    yr[tid]       = __float2bfloat16((v0 - mu) * rstd * g[tid]       + b[tid]);
    yr[tid + 256] = __float2bfloat16((v1 - mu) * rstd * g[tid + 256] + b[tid + 256]);
    yr[tid + 512] = __float2bfloat16((v2 - mu) * rstd * g[tid + 512] + b[tid + 512]);
}

// ---- bf16 MFMA GEMM, m97 structure: 128x128 tile, BK=32, global_load_lds
// width=16 staging, 4 waves in 2x2, each 4x4 16x16 acc tiles.
// A: MxK row-major bf16 (contiguous). Bt: NxK row-major bf16.
// EP: 0=qkv head-scatter(bf16)  1=proj+residual+window-unpartition(fp32)
//     2=GELU->bf16 hidden       3=add into out(fp32)
template<int EP>
__global__ __launch_bounds__(256)
void gemm_k(const __hip_bfloat16* __restrict__ A,
            const __hip_bfloat16* __restrict__ Bt,
            const float* __restrict__ bias,
            int M, int N, int K,
            __hip_bfloat16* __restrict__ oq, __hip_bfloat16* __restrict__ okk,
            __hip_bfloat16* __restrict__ ov,
            float* __restrict__ of, const float* __restrict__ resid,
            __hip_bfloat16* __restrict__ oh,
            int win_base, int m_base)
{
    __shared__ unsigned short As[128 * 32];
    __shared__ unsigned short Bs[128 * 32];

    int tid = threadIdx.x;
    int wave = tid >> 6, lane = tid & 63;
    int n16 = lane & 15, quad = lane >> 4;
    int bm = blockIdx.x * 128;
    int bn = blockIdx.y * 128;

    const unsigned short* Au = (const unsigned short*)A;
    const unsigned short* Bu = (const unsigned short*)Bt;

    // staging: per issue a wave covers 16 rows (64 lanes x 16B = 16 rows x 64B)
    int sr = wave * 16 + (lane >> 2);
    int ra0 = bm + sr;        if (ra0 >= M) ra0 = M - 1;
    int ra1 = bm + 64 + sr;   if (ra1 >= M) ra1 = M - 1;
    const unsigned short* gA0 = Au + (size_t)ra0 * K + (lane & 3) * 8;
    const unsigned short* gA1 = Au + (size_t)ra1 * K + (lane & 3) * 8;
    const unsigned short* gB0 = Bu + (size_t)(bn + sr) * K + (lane & 3) * 8;
    const unsigned short* gB1 = gB0 + (size_t)64 * K;
    unsigned short* lA0 = As + wave * 16 * 32;
    unsigned short* lA1 = As + (64 + wave * 16) * 32;
    unsigned short* lB0 = Bs + wave * 16 * 32;
    unsigned short* lB1 = Bs + (64 + wave * 16) * 32;

    int rowblk = (wave >> 1) * 64, colblk = (wave & 1) * 64;

    floatx4 acc[4][4] = {};

    for (int k0 = 0; k0 < K; k0 += 32) {
        __syncthreads();
        gload16(gA0, lA0);
        gload16(gA1, lA1);
        gload16(gB0, lB0);
        gload16(gB1, lB1);
        gA0 += 32; gA1 += 32; gB0 += 32; gB1 += 32;
        __syncthreads();
        short8 af[4], bf[4];
        #pragma unroll
        for (int mt = 0; mt < 4; ++mt)
            af[mt] = *(const short8*)&As[(rowblk + mt * 16 + n16) * 32 + quad * 8];
        #pragma unroll
        for (int nt = 0; nt < 4; ++nt)
            bf[nt] = *(const short8*)&Bs[(colblk + nt * 16 + n16) * 32 + quad * 8];
        #pragma unroll
        for (int mt = 0; mt < 4; ++mt)
            #pragma unroll
            for (int nt = 0; nt < 4; ++nt)
                acc[mt][nt] = __builtin_amdgcn_mfma_f32_16x16x32_bf16(
                    af[mt], bf[nt], acc[mt][nt], 0, 0, 0);
    }

    // C/D layout: col = lane&15, row = quad*4 + reg.
    #pragma unroll
    for (int mt = 0; mt < 4; ++mt) {
        #pragma unroll
        for (int nt = 0; nt < 4; ++nt) {
            int col = bn + colblk + nt * 16 + n16;
            float bcol = bias[col];
            #pragma unroll
            for (int r = 0; r < 4; ++r) {
                int row = bm + rowblk + mt * 16 + quad * 4 + r;
                if (row >= M) continue;
                float val = acc[mt][nt][r] + bcol;
                if (EP == 0) {
                    int which = col / HS;
                    int hd = col - which * HS;
                    int head = hd >> 6, d = hd & 63;
                    int lwin = row / TOK, tok = row - lwin * TOK;
                    size_t idx = ((size_t)((lwin * NHEADS + head) * TOK + tok)) * HD + d;
                    __hip_bfloat16* dst = (which == 0) ? oq : ((which == 1) ? okk : ov);
                    dst[idx] = __float2bfloat16(val);
                } else if (EP == 1) {
                    int lwin = row / TOK, tok = row - lwin * TOK;
                    int win = win_base + lwin;
                    int bb = win / WIN_PER_B, rr = win - bb * WIN_PER_B;
                    int wi = rr / NSIDE, wj = rr - wi * NSIDE;
                    int ti = tok / WSZ, tj = tok - ti * WSZ;
                    int h = wi * WSZ + ti, w = wj * WSZ + tj;
                    if (h < HWDIM && w < HWDIM) {
                        size_t idx = ((size_t)((bb * HWDIM + h) * HWDIM + w)) * HS + col;
                        of[idx] = resid[idx] + val;
                    }
                } else if (EP == 2) {
                    float ge = 0.5f * val * (1.0f + erff(val * 0.70710678118654752f));
                    oh[(size_t)row * N + col] = __float2bfloat16(ge);
                } else {
                    size_t idx = ((size_t)(m_base + row)) * HS + col;
                    of[idx] += val;
                }
            }
        }
    }
}

// ---- MFMA attention. One block per (local window, head); 4 waves. ----
__global__ __launch_bounds__(256)
void attn_k(const __hip_bfloat16* __restrict__ qb, const __hip_bfloat16* __restrict__ kb,
            const __hip_bfloat16* __restrict__ vb,
            const float* __restrict__ rph, const float* __restrict__ rpw,
            __hip_bfloat16* __restrict__ ao)
{
    __shared__ __align__(16) unsigned short lds[31904];
    unsigned short* Ks = lds;            // stride 72
    unsigned short* Vt = lds + 14112;    // stride 224
    unsigned short* scr = lds + 28448;   // 4 x 864

    int bid = blockIdx.x;
    int lwin = bid / NHEADS, head = bid - lwin * NHEADS;
    size_t base = (size_t)(lwin * NHEADS + head) * TOK * HD;
    const unsigned short* q = (const unsigned short*)qb + base;
    const unsigned short* k = (const unsigned short*)kb + base;
    const unsigned short* v = (const unsigned short*)vb + base;

    int tid = threadIdx.x;
    int wave = tid >> 6, lane = tid & 63;
    int n16 = lane & 15, quad = lane >> 4;

    // loop-invariant rel-table B fragments (bf16 from fp32 tables)
    short8 btab[4][2];
    #pragma unroll
    for (int nt = 0; nt < 4; ++nt) {
        int n = nt * 16 + n16;
        #pragma unroll
        for (int kh = 0; kh < 2; ++kh) {
            short8 f = {0, 0, 0, 0, 0, 0, 0, 0};
            if (n < 54) {
                const float* src = (n < 27) ? (rph + (size_t)n * HD)
                                            : (rpw + (size_t)(n - 27) * HD);
                const float4* s4 = (const float4*)(src + kh * 32 + quad * 8);
                float4 a = s4[0], b = s4[1];
                f[0] = (short)f2bu(a.x); f[1] = (short)f2bu(a.y);
                f[2] = (short)f2bu(a.z); f[3] = (short)f2bu(a.w);
                f[4] = (short)f2bu(b.x); f[5] = (short)f2bu(b.y);
                f[6] = (short)f2bu(b.z); f[7] = (short)f2bu(b.w);
            }
            btab[nt][kh] = f;
        }
    }

    for (int idx = tid; idx < 1568; idx += 256) {
        int row = idx >> 3, q8 = (idx & 7) << 3;
        *(uint4*)&Ks[row * 72 + q8] = *(const uint4*)(k + (size_t)row * HD + q8);
    }
    for (int s = tid; s < 49 * 64; s += 256) {
        int g = s >> 6, d = s & 63;
        unsigned int w0 = ((unsigned int)v[(size_t)(4 * g + 0) * HD + d]) |
                          ((unsigned int)v[(size_t)(4 * g + 1) * HD + d] << 16);
        unsigned int w1 = ((unsigned int)v[(size_t)(4 * g + 2) * HD + d]) |
                          ((unsigned int)v[(size_t)(4 * g + 3) * HD + d] << 16);
        uint2 pk = {w0, w1};
        *(uint2*)&Vt[d * 224 + 4 * g] = pk;
    }
    for (int s = tid; s < 448; s += 256) {
        int r = s / 7, c = 196 + (s - r * 7) * 4;
        uint2 z = {0u, 0u};
        *(uint2*)&Vt[r * 224 + c] = z;
    }
    __syncthreads();

    unsigned short* myscr = &scr[wave * 864];
    int rl0 = quad * 4;

    for (int qt = wave; qt < 13; qt += 4) {
        int qrow = qt * 16 + n16;
        int qr = qrow < 196 ? qrow : 195;

        short8 qf0 = *(const short8*)(q + (size_t)qr * HD + quad * 8);
        short8 qf1 = *(const short8*)(q + (size_t)qr * HD + 32 + quad * 8);

        // rel bias via MFMA: rel[16 rows][54 cols] -> scr
        #pragma unroll
        for (int nt = 0; nt < 4; ++nt) {
            floatx4 cr = {0.f, 0.f, 0.f, 0.f};
            cr = __builtin_amdgcn_mfma_f32_16x16x32_bf16(qf0, btab[nt][0], cr, 0, 0, 0);
            cr = __builtin_amdgcn_mfma_f32_16x16x32_bf16(qf1, btab[nt][1], cr, 0, 0, 0);
            int c = nt * 16 + n16;
            if (c < 54) {
                #pragma unroll
                for (int r = 0; r < 4; ++r)
                    myscr[(rl0 + r) * 54 + c] = f2bu(cr[r]);
            }
        }

        // S = Q K^T
        floatx4 S[13];
        #pragma unroll
        for (int nt = 0; nt < 13; ++nt) {
            short8 kf0 = *(const short8*)&Ks[(nt * 16 + n16) * 72 + quad * 8];
            short8 kf1 = *(const short8*)&Ks[(nt * 16 + n16) * 72 + 32 + quad * 8];
            floatx4 a = {0.f, 0.f, 0.f, 0.f};
            a = __builtin_amdgcn_mfma_f32_16x16x32_bf16(qf0, kf0, a, 0, 0, 0);
            a = __builtin_amdgcn_mfma_f32_16x16x32_bf16(qf1, kf1, a, 0, 0, 0);
            S[nt] = a;
        }

        int ti4[4], tj4[4];
        #pragma unroll
        for (int r = 0; r < 4; ++r) {
            int grow = qt * 16 + rl0 + r;
            ti4[r] = grow / WSZ;
            tj4[r] = grow - ti4[r] * WSZ;
        }

        #pragma unroll
        for (int nt = 0; nt < 13; ++nt) {
            int col = nt * 16 + n16;
            int ki = col / WSZ, kj = col - ki * WSZ;
            #pragma unroll
            for (int r = 0; r < 4; ++r) {
                float rh = bf2f(myscr[(rl0 + r) * 54 + (ti4[r] - ki + 13)]);
                float rw = bf2f(myscr[(rl0 + r) * 54 + (40 + tj4[r] - kj)]);
                S[nt][r] = fmaf(S[nt][r], 0.125f, rh + rw);
            }
        }
        if (n16 >= 4) {
            #pragma unroll
            for (int r = 0; r < 4; ++r) S[12][r] = -1e30f;
        }

        float mxr[4] = {-3e30f, -3e30f, -3e30f, -3e30f};
        #pragma unroll
        for (int nt = 0; nt < 13; ++nt)
            #pragma unroll
            for (int r = 0; r < 4; ++r) mxr[r] = fmaxf(mxr[r], S[nt][r]);
        #pragma unroll
        for (int m = 1; m <= 8; m <<= 1)
            #pragma unroll
            for (int r = 0; r < 4; ++r) mxr[r] = fmaxf(mxr[r], __shfl_xor(mxr[r], m, 64));
        float sum[4] = {0.f, 0.f, 0.f, 0.f};
        #pragma unroll
        for (int nt = 0; nt < 13; ++nt)
            #pragma unroll
            for (int r = 0; r < 4; ++r) {
                float e = __expf(S[nt][r] - mxr[r]);
                S[nt][r] = e;
                sum[r] += e;
            }
        #pragma unroll
        for (int m = 1; m <= 8; m <<= 1)
            #pragma unroll
            for (int r = 0; r < 4; ++r) sum[r] += __shfl_xor(sum[r], m, 64);
        float inv[4];
        #pragma unroll
        for (int r = 0; r < 4; ++r) inv[r] = 1.0f / sum[r];

        floatx4 O[4] = {{0.f,0.f,0.f,0.f},{0.f,0.f,0.f,0.f},{0.f,0.f,0.f,0.f},{0.f,0.f,0.f,0.f}};
        #pragma unroll
        for (int ks = 0; ks < 7; ++ks) {
            #pragma unroll
            for (int r = 0; r < 4; ++r) {
                myscr[(rl0 + r) * 40 + n16] = f2bu(S[2 * ks][r] * inv[r]);
                myscr[(rl0 + r) * 40 + 16 + n16] =
                    (2 * ks + 1 < 13) ? f2bu(S[2 * ks + 1][r] * inv[r]) : (unsigned short)0;
            }
            short8 pf = *(const short8*)&myscr[n16 * 40 + quad * 8];
            #pragma unroll
            for (int nt4 = 0; nt4 < 4; ++nt4) {
                short8 vf = *(const short8*)&Vt[(nt4 * 16 + n16) * 224 + ks * 32 + quad * 8];
                O[nt4] = __builtin_amdgcn_mfma_f32_16x16x32_bf16(pf, vf, O[nt4], 0, 0, 0);
            }
        }

        #pragma unroll
        for (int nt4 = 0; nt4 < 4; ++nt4) {
            int d = nt4 * 16 + n16;
            #pragma unroll
            for (int r = 0; r < 4; ++r) {
                int row = qt * 16 + rl0 + r;
                if (row < 196) {
                    ao[((size_t)(lwin * TOK + row)) * HS + head * HD + d] =
                        __float2bfloat16(O[nt4][r]);
                }
            }
        }
    }
}

extern "C" void kernel_launch(void* const* d_in, const int* in_sizes, int n_in,
                              void* d_out, int out_size, void* d_ws, size_t ws_size,
                              hipStream_t stream)
{
    const float* x      = (const float*)d_in[0];
    const float* ln1_g  = (const float*)d_in[1];
    const float* ln1_b  = (const float*)d_in[2];
    const float* qkv_w  = (const float*)d_in[3];
    const float* qkv_b  = (const float*)d_in[4];
    const float* proj_w = (const float*)d_in[5];
    const float* proj_b = (const float*)d_in[6];
    const float* rph    = (const float*)d_in[7];
    const float* rpw    = (const float*)d_in[8];
    const float* ln2_g  = (const float*)d_in[9];
    const float* ln2_b  = (const float*)d_in[10];
    const float* mlp_w1 = (const float*)d_in[11];
    const float* mlp_b1 = (const float*)d_in[12];
    const float* mlp_w2 = (const float*)d_in[13];
    const float* mlp_b2 = (const float*)d_in[14];
    float* out = (float*)d_out;

    char* ws = (char*)d_ws;
    __hip_bfloat16* wqkv  = (__hip_bfloat16*)(ws + 0);          // [2304][768]
    __hip_bfloat16* wproj = (__hip_bfloat16*)(ws + 3538944);    // [768][768]
    __hip_bfloat16* wm1   = (__hip_bfloat16*)(ws + 4718592);    // [3072][768]
    __hip_bfloat16* wm2   = (__hip_bfloat16*)(ws + 9437184);    // [768][3072]
    __hip_bfloat16* ybuf  = (__hip_bfloat16*)(ws + 14155776);   // 39200x768 gathered / 32768x768 ln2
    char* R2 = ws + 74366976;
    __hip_bfloat16* qc  = (__hip_bfloat16*)(R2);
    __hip_bfloat16* kc  = (__hip_bfloat16*)(R2 + 7526400);
    __hip_bfloat16* vc  = (__hip_bfloat16*)(R2 + 15052800);
    __hip_bfloat16* ao  = (__hip_bfloat16*)(R2 + 22579200);
    __hip_bfloat16* hid = (__hip_bfloat16*)(R2);                // [4096][3072]

    cvt_t_k<<<dim3(6912), 256, 0, stream>>>(qkv_w,  wqkv,  768, 2304);
    cvt_t_k<<<dim3(2304), 256, 0, stream>>>(proj_w, wproj, 768, 768);
    cvt_t_k<<<dim3(9216), 256, 0, stream>>>(mlp_w1, wm1,   768, 3072);
    cvt_t_k<<<dim3(9216), 256, 0, stream>>>(mlp_w2, wm2,  3072, 768);

    // zero gathered-y buffer (pad rows must be 0 = reference's padded y rows)
    hipMemsetAsync(ybuf, 0, (size_t)200 * TOK * HS * 2, stream);
    // LN1 -> gathered window-token layout
    ln_k<1><<<dim3(32768), 256, 0, stream>>>(x, ln1_g, ln1_b, ybuf);

    for (int wc = 0; wc < 8; ++wc) {
        gemm_k<0><<<dim3(39, 18), 256, 0, stream>>>(
            ybuf + (size_t)wc * MCH * HS, wqkv, qkv_b, MCH, 2304, 768,
            qc, kc, vc, nullptr, nullptr, nullptr, wc * WCHUNK, 0);
        attn_k<<<dim3(300), 256, 0, stream>>>(qc, kc, vc, rph, rpw, ao);
        gemm_k<1><<<dim3(39, 6), 256, 0, stream>>>(
            ao, wproj, proj_b, MCH, 768, 768,
            nullptr, nullptr, nullptr, out, x, nullptr, wc * WCHUNK, 0);
    }

    // LN2 (natural layout)
    ln_k<0><<<dim3(32768), 256, 0, stream>>>(out, ln2_g, ln2_b, ybuf);

    for (int mc = 0; mc < 8; ++mc) {
        gemm_k<2><<<dim3(32, 24), 256, 0, stream>>>(
            ybuf + (size_t)mc * MLPCH * HS, wm1, mlp_b1, MLPCH, 3072, 768,
            nullptr, nullptr, nullptr, nullptr, nullptr, hid, 0, 0);
        gemm_k<3><<<dim3(32, 6), 256, 0, stream>>>(
            hid, wm2, mlp_b2, MLPCH, 768, 3072,
            nullptr, nullptr, nullptr, out, nullptr, nullptr, 0, mc * MLPCH);
    }
}